// Round 1
// 546.147 us; speedup vs baseline: 1.1857x; 1.1857x over previous
//
#include <hip/hip_runtime.h>
#include <stdint.h>

#define E_ 64
#define KTOP 4
#define H_ 2048
#define I_ 1536
#define GS_ 128
#define T_ 1024
#define CAP 128

typedef __attribute__((ext_vector_type(8))) short short8;
typedef __attribute__((ext_vector_type(4))) float f32x4;

__device__ __forceinline__ uint32_t bf16rne(float f) {
  uint32_t u = __float_as_uint(f);
  return (u + 0x7FFFu + ((u >> 16) & 1u)) >> 16;
}
__device__ __forceinline__ float bf16f(uint32_t b) {
  return __uint_as_float(b << 16);
}

// ---------------- cast x (f32 -> bf16) ----------------
__global__ void cast_x_kernel(const float* __restrict__ x, uint16_t* __restrict__ xb, int n4) {
  int i = blockIdx.x * blockDim.x + threadIdx.x;
  if (i >= n4) return;
  float4 v = ((const float4*)x)[i];
  uint32_t lo = bf16rne(v.x) | (bf16rne(v.y) << 16);
  uint32_t hi = bf16rne(v.z) | (bf16rne(v.w) << 16);
  uint2 r; r.x = lo; r.y = hi;
  ((uint2*)xb)[i] = r;
}

// ---------------- transpose gate_w [E][H] -> gwT [H][E] ----------------
__global__ void transpose_gw_kernel(const float* __restrict__ gw, float* __restrict__ gwT) {
  int o = blockIdx.x * 256 + threadIdx.x;  // 131072
  int k = o >> 6, e = o & 63;
  gwT[o] = gw[(long)e * H_ + k];
}

// ---------------- routing: coalesced logits via gwT, then top-4 ----------------
__global__ __launch_bounds__(256) void routing_kernel(
    const float* __restrict__ x, const float* __restrict__ gwT,
    float* __restrict__ tw, int* __restrict__ ti) {
  int t = blockIdx.x;
  int tid = threadIdx.x;
  __shared__ float xs[H_];
  __shared__ float lgp[4][E_];
  const float4* xp = (const float4*)(x + (long)t * H_);
  ((float4*)xs)[tid] = xp[tid];
  ((float4*)xs)[tid + 256] = xp[tid + 256];
  __syncthreads();
  int e = tid & 63, w4 = tid >> 6;  // wave w4 covers k in [w4*512, w4*512+512)
  const float* gp = gwT + (long)w4 * 512 * E_ + e;
  const float* xw = xs + w4 * 512;
  float a0 = 0.f, a1 = 0.f, a2 = 0.f, a3 = 0.f;
#pragma unroll 4
  for (int k = 0; k < 512; k += 4) {
    a0 += xw[k]     * gp[(long)(k)     * E_];
    a1 += xw[k + 1] * gp[(long)(k + 1) * E_];
    a2 += xw[k + 2] * gp[(long)(k + 2) * E_];
    a3 += xw[k + 3] * gp[(long)(k + 3) * E_];
  }
  lgp[w4][e] = (a0 + a1) + (a2 + a3);
  __syncthreads();
  if (tid < 64) {
    int lane = tid;
    float v = lgp[0][lane] + lgp[1][lane] + lgp[2][lane] + lgp[3][lane];
    float vals[KTOP]; int ids[KTOP];
#pragma unroll
    for (int k = 0; k < KTOP; k++) {
      float bv = v; int bi = lane;
      for (int off = 32; off; off >>= 1) {
        float ov = __shfl_xor(bv, off);
        int oi = __shfl_xor(bi, off);
        if (ov > bv || (ov == bv && oi < bi)) { bv = ov; bi = oi; }
      }
      vals[k] = bv; ids[k] = bi;
      if (lane == bi) v = -3.4e38f;
    }
    if (lane == 0) {
      float m = vals[0];
      float p[KTOP]; float s = 0.f;
#pragma unroll
      for (int k = 0; k < KTOP; k++) { p[k] = expf(vals[k] - m); s += p[k]; }
      float inv = 1.f / s;
#pragma unroll
      for (int k = 0; k < KTOP; k++) {
        tw[t * KTOP + k] = p[k] * inv;
        ti[t * KTOP + k] = ids[k];
      }
    }
  }
}

// ---------------- dispatch: stable rank-within-expert + capacity ----------------
__global__ void assign_kernel(const int* __restrict__ ti, int* __restrict__ counts,
                              int* __restrict__ tlist, int* __restrict__ slot_of) {
  int e = blockIdx.x;
  int lane = threadIdx.x;  // 64
  int cnt = 0;
  for (int base = 0; base < T_ * KTOP; base += 64) {
    int a = base + lane;
    int ef = ti[a];
    unsigned long long m = __ballot(ef == e);
    if (ef == e) {
      int rank = cnt + __popcll(m & ((1ull << lane) - 1ull));
      if (rank < CAP) {
        tlist[e * CAP + rank] = a >> 2;
        slot_of[a] = e * CAP + rank;
      } else {
        slot_of[a] = -1;
      }
    }
    cnt += __popcll(m);
  }
  if (lane == 0) counts[e] = min(cnt, CAP);
}

// ---------------- generic FP4-dequant GEMM, pipelined ----------------
// Grid: (N/128, nE + nShared). blockIdx.y < nE -> expert slice (rowids/counts,
// weight set 1, out1); else shared M-tile (yb-nE), weight set 2, out2.
// Tile M=128, N=128, BK=64, double-buffered A (global_load_lds), reg-prefetched
// B-packed one tile ahead, raw barriers with counted vmcnt(6).
// LDS: As 2x16KB + Bs 16KB = 48 KB -> 3 blocks/CU.
__global__ __launch_bounds__(256, 3) void gemm_fp4_kernel(
    const uint16_t* __restrict__ A1, const uint16_t* __restrict__ A2, int ldA,
    const int* __restrict__ rowids, const int* __restrict__ counts, int nE,
    const int* __restrict__ packed1, long p_stride,
    const float* __restrict__ scales1, long s_stride,
    const int* __restrict__ packed2, const float* __restrict__ scales2,
    void* __restrict__ out1, int of1, void* __restrict__ out2, int of2,
    int K, int N) {
  __shared__ uint16_t As[2][128 * 64];   // 2 x 16 KB
  __shared__ uint16_t Bs[8 * 128 * 8];   // 16 KB, layout [kc][n][8]

  int yb = blockIdx.y, bn = blockIdx.x;
  int tid = threadIdx.x;
  int wave = tid >> 6, lane = tid & 63;

  const uint16_t* A;
  const int* packed_e;
  const float* scales_e;
  char* outp;
  int of32, row_base, valid;
  const int* rid = nullptr;
  if (yb < nE) {
    int e = yb;
    valid = counts[e];
    if (valid <= 0) return;
    if (valid > 128) valid = 128;
    if (rowids) rid = rowids + e * CAP;
    row_base = e * CAP;
    A = A1;
    packed_e = packed1 + (long)e * p_stride;
    scales_e = scales1 + (long)e * s_stride;
    outp = (char*)out1; of32 = of1;
  } else {
    valid = 128;
    row_base = (yb - nE) * 128;
    A = A2;
    packed_e = packed2;
    scales_e = scales2;
    outp = (char*)out2; of32 = of2;
  }

  // A staging: 16 insts of 1KB cover 128 rows x 64 k; 4 insts/thread-wave.
  // inst covers rows inst*8..+8 (128 B/row); lane: row += lane>>3, chunk c_s=lane&7,
  // source chunk g = c_s ^ (r&7)  (XOR swizzle matched on the read side).
  const uint16_t* asrc[4];
  int adst[4];
#pragma unroll
  for (int ii = 0; ii < 4; ii++) {
    int inst = wave * 4 + ii;
    int r = inst * 8 + (lane >> 3);
    int rr = r < valid ? r : valid - 1;
    long arow = rid ? (long)rid[rr] : (long)(row_base + rr);
    int g = (lane & 7) ^ (r & 7);
    asrc[ii] = A + arow * (long)ldA + (g << 3);
    adst[ii] = inst * 512;  // elems
  }

  // B: thread pair per n-row; each thread handles 4 packed words (32 k) per tile.
  int j = tid >> 1, wseg = tid & 1;
  int n_col = bn * 128 + j;
  const int* prow = packed_e + (long)n_col * (K >> 3) + wseg * 4;
  uint16_t* bdst = Bs + ((long)(wseg * 4) * 128 + j) * 8;

  f32x4 acc[4][4];
#pragma unroll
  for (int a0 = 0; a0 < 4; a0++)
#pragma unroll
    for (int b0 = 0; b0 < 4; b0++) {
      f32x4 z = {0.f, 0.f, 0.f, 0.f};
      acc[a0][b0] = z;
    }

  int wm = wave >> 1, wn = wave & 1;
  int q = lane >> 4, r16 = lane & 15;

  int nk = K >> 6;

  // ---- prologue: tile 0 in flight
  uint4 bpk_c = *(const uint4*)prow;
  float scl_c = scales_e[n_col];
#pragma unroll
  for (int ii = 0; ii < 4; ii++)
    __builtin_amdgcn_global_load_lds(
        (const __attribute__((address_space(1))) unsigned int*)asrc[ii],
        (__attribute__((address_space(3))) unsigned int*)(&As[0][0] + adst[ii]),
        16, 0, 0);
  uint4 bpk_n = bpk_c;
  float scl_n = scl_c;

  for (int it = 0; it < nk; ++it) {
    int b = it & 1;
    int kt2 = (it + 1) << 6;
    int pf = (it + 1 < nk);
    // ---- prefetch tile it+1: exactly 6 vmem ops (1 dwordx4 + 1 dword + 4 lds-loads)
    if (pf) {
      bpk_n = *(const uint4*)(prow + (kt2 >> 3));
      scl_n = scales_e[(long)(kt2 >> 7) * N + n_col];
      uint16_t* ab = &As[b ^ 1][0];
#pragma unroll
      for (int ii = 0; ii < 4; ii++)
        __builtin_amdgcn_global_load_lds(
            (const __attribute__((address_space(1))) unsigned int*)(asrc[ii] + kt2),
            (__attribute__((address_space(3))) unsigned int*)(ab + adst[ii]),
            16, 0, 0);
    }
    // ---- dequant current B-packed -> Bs (scaled byte-LUT + v_perm)
    {
      float s = scl_c;
      uint32_t b1 = bf16rne(s), b15 = bf16rne(1.5f * s);
      uint32_t t0 = 0, t1 = b1 - 0x80, t2 = b1, t3 = b15;
      uint32_t t4 = b1 + 0x80, t5 = b15 + 0x80, t6 = b1 + 0x100, t7 = b15 + 0x100;
      uint32_t tll = (t0 & 0xFF) | ((t1 & 0xFF) << 8) | ((t2 & 0xFF) << 16) | ((t3 & 0xFF) << 24);
      uint32_t tlh = (t4 & 0xFF) | ((t5 & 0xFF) << 8) | ((t6 & 0xFF) << 16) | ((t7 & 0xFF) << 24);
      uint32_t thl = (t0 >> 8) | ((t1 >> 8) << 8) | ((t2 >> 8) << 16) | ((t3 >> 8) << 24);
      uint32_t thh = (t4 >> 8) | ((t5 >> 8) << 8) | ((t6 >> 8) << 16) | ((t7 >> 8) << 24);
      uint32_t wsv[4] = {bpk_c.x, bpk_c.y, bpk_c.z, bpk_c.w};
#pragma unroll
      for (int w = 0; w < 4; w++) {
        uint32_t wv = wsv[w];
        uint32_t ev = wv & 0x07070707u;
        uint32_t od = (wv >> 4) & 0x07070707u;
        uint32_t se = (wv << 4) & 0x80808080u;
        uint32_t so = wv & 0x80808080u;
        uint32_t he = __builtin_amdgcn_perm(thh, thl, ev) | se;
        uint32_t ho = __builtin_amdgcn_perm(thh, thl, od) | so;
        uint32_t le = __builtin_amdgcn_perm(tlh, tll, ev);
        uint32_t lo = __builtin_amdgcn_perm(tlh, tll, od);
        uint32_t v02 = __builtin_amdgcn_perm(he, le, 0x05010400u);
        uint32_t v46 = __builtin_amdgcn_perm(he, le, 0x07030602u);
        uint32_t v13 = __builtin_amdgcn_perm(ho, lo, 0x05010400u);
        uint32_t v57 = __builtin_amdgcn_perm(ho, lo, 0x07030602u);
        uint4 qv;
        qv.x = __builtin_amdgcn_perm(v13, v02, 0x05040100u);
        qv.y = __builtin_amdgcn_perm(v13, v02, 0x07060302u);
        qv.z = __builtin_amdgcn_perm(v57, v46, 0x05040100u);
        qv.w = __builtin_amdgcn_perm(v57, v46, 0x07060302u);
        *(uint4*)(bdst + (long)w * 1024) = qv;
      }
    }
    // ---- barrier 1: current A-tile landed (keep 6 prefetch ops in flight), Bs written
    if (pf) asm volatile("s_waitcnt vmcnt(6) lgkmcnt(0)" ::: "memory");
    else    asm volatile("s_waitcnt vmcnt(0) lgkmcnt(0)" ::: "memory");
    __builtin_amdgcn_sched_barrier(0);
    __builtin_amdgcn_s_barrier();
    __builtin_amdgcn_sched_barrier(0);

    // ---- MFMA: wave tile 64x64, 2 k-steps of 4x4 16x16x32
    const uint16_t* asb = &As[b][0];
    __builtin_amdgcn_s_setprio(1);
#pragma unroll
    for (int kk = 0; kk < 64; kk += 32) {
      int kc4 = (kk >> 3) + q;
      short8 af[4], bfr[4];
#pragma unroll
      for (int fm = 0; fm < 4; fm++) {
        int m = wm * 64 + fm * 16 + r16;
        af[fm] = *(const short8*)(asb + (long)m * 64 + ((kc4 ^ (m & 7)) << 3));
      }
#pragma unroll
      for (int fn = 0; fn < 4; fn++) {
        int n = wn * 64 + fn * 16 + r16;
        bfr[fn] = *(const short8*)(Bs + ((long)kc4 * 128 + n) * 8);
      }
#pragma unroll
      for (int fm = 0; fm < 4; fm++)
#pragma unroll
        for (int fn = 0; fn < 4; fn++)
          acc[fm][fn] = __builtin_amdgcn_mfma_f32_16x16x32_bf16(af[fm], bfr[fn], acc[fm][fn], 0, 0, 0);
    }
    __builtin_amdgcn_s_setprio(0);
    // ---- barrier 2: all waves done reading before next iter overwrites As/Bs
    __builtin_amdgcn_sched_barrier(0);
    __builtin_amdgcn_s_barrier();
    __builtin_amdgcn_sched_barrier(0);
    bpk_c = bpk_n;
    scl_c = scl_n;
  }

  // ---- epilogue: D mapping col=lane&15, row=(lane>>4)*4+reg
  int outr0 = wm * 64 + (q << 2);
  int outc0 = bn * 128 + wn * 64 + r16;
#pragma unroll
  for (int fm = 0; fm < 4; fm++)
#pragma unroll
    for (int fn = 0; fn < 4; fn++) {
#pragma unroll
      for (int r = 0; r < 4; r++) {
        int rloc = outr0 + fm * 16 + r;
        if (rloc >= valid) continue;
        long row = row_base + rloc;
        long col = outc0 + fn * 16;
        float vv = acc[fm][fn][r];
        if (of32) ((float*)outp)[row * N + col] = vv;
        else ((uint16_t*)outp)[row * N + col] = (uint16_t)bf16rne(vv);
      }
    }
}

// ---------------- h = silu(g) * u  (bf16, elementwise x8) ----------------
__global__ void silu_mul_kernel(const uint16_t* __restrict__ g, const uint16_t* __restrict__ u,
                                uint16_t* __restrict__ h, int n8) {
  int i = blockIdx.x * blockDim.x + threadIdx.x;
  if (i >= n8) return;
  uint4 gv = ((const uint4*)g)[i];
  uint4 uv = ((const uint4*)u)[i];
  uint32_t gw[4] = {gv.x, gv.y, gv.z, gv.w};
  uint32_t uw[4] = {uv.x, uv.y, uv.z, uv.w};
  uint32_t rw[4];
#pragma unroll
  for (int w = 0; w < 4; w++) {
    float g0 = bf16f(gw[w] & 0xFFFFu), g1 = bf16f(gw[w] >> 16);
    float u0 = bf16f(uw[w] & 0xFFFFu), u1 = bf16f(uw[w] >> 16);
    float r0 = g0 / (1.f + __expf(-g0)) * u0;
    float r1 = g1 / (1.f + __expf(-g1)) * u1;
    rw[w] = bf16rne(r0) | (bf16rne(r1) << 16);
  }
  uint4 res; res.x = rw[0]; res.y = rw[1]; res.z = rw[2]; res.w = rw[3];
  ((uint4*)h)[i] = res;
}

// ---------------- combine: y[t] += sum_k w_k * eout[slot_k] ----------------
__global__ __launch_bounds__(256) void combine_kernel(
    float* __restrict__ y, const uint16_t* __restrict__ eout,
    const int* __restrict__ slot_of, const float* __restrict__ tw) {
  int t = blockIdx.x;
  int c = threadIdx.x * 8;
  float* yp = y + (long)t * H_ + c;
  float4 y0 = ((float4*)yp)[0];
  float4 y1 = ((float4*)yp)[1];
  float a[8] = {y0.x, y0.y, y0.z, y0.w, y1.x, y1.y, y1.z, y1.w};
#pragma unroll
  for (int k = 0; k < KTOP; k++) {
    int s = slot_of[t * KTOP + k];
    float w = tw[t * KTOP + k];
    if (s < 0) continue;
    uint4 v = *(const uint4*)(eout + (long)s * H_ + c);
    uint32_t vw[4] = {v.x, v.y, v.z, v.w};
#pragma unroll
    for (int jj = 0; jj < 4; jj++) {
      a[2 * jj]     += w * bf16f(vw[jj] & 0xFFFFu);
      a[2 * jj + 1] += w * bf16f(vw[jj] >> 16);
    }
  }
  float4 o0 = {a[0], a[1], a[2], a[3]};
  float4 o1 = {a[4], a[5], a[6], a[7]};
  ((float4*)yp)[0] = o0;
  ((float4*)yp)[1] = o1;
}

extern "C" void kernel_launch(void* const* d_in, const int* in_sizes, int n_in,
                              void* d_out, int out_size, void* d_ws, size_t ws_size,
                              hipStream_t stream) {
  const float* x              = (const float*)d_in[0];
  const float* gate_w         = (const float*)d_in[1];
  const float* gate_scales    = (const float*)d_in[2];
  const float* up_scales      = (const float*)d_in[3];
  const float* down_scales    = (const float*)d_in[4];
  const float* sh_gate_scales = (const float*)d_in[5];
  const float* sh_up_scales   = (const float*)d_in[6];
  const float* sh_down_scales = (const float*)d_in[7];
  const int* gate_packed      = (const int*)d_in[8];
  const int* up_packed        = (const int*)d_in[9];
  const int* down_packed      = (const int*)d_in[10];
  const int* sh_gate_packed   = (const int*)d_in[11];
  const int* sh_up_packed     = (const int*)d_in[12];
  const int* sh_down_packed   = (const int*)d_in[13];
  float* y = (float*)d_out;

  char* ws = (char*)d_ws;
  uint16_t* xb     = (uint16_t*)(ws);               // 4,194,304 B
  float*    tw     = (float*)(ws + 4194304);
  int*      ti     = (int*)(ws + 4210688);
  int*      counts = (int*)(ws + 4227072);
  int*      tlist  = (int*)(ws + 4227328);
  int*      slot_of= (int*)(ws + 4260096);
  uint16_t* gbuf   = (uint16_t*)(ws + 4276480);     // 25,165,824 (later h)
  float*    gwT    = (float*)(ws + 4276480);        // 524,288 B, aliases gbuf (dead before gate GEMM)
  uint16_t* ubuf   = (uint16_t*)(ws + 29442304);    // 25,165,824
  uint16_t* eout   = (uint16_t*)(ws + 29442304);    // 33,554,432 (aliases dead ubuf)
  uint16_t* gsbuf  = (uint16_t*)(ws + 62996736);    // 3,145,728 (later hs)
  uint16_t* usbuf  = (uint16_t*)(ws + 66142464);    // 3,145,728; end ~69.3 MB

  cast_x_kernel<<<2048, 256, 0, stream>>>(x, xb, T_ * H_ / 4);
  transpose_gw_kernel<<<512, 256, 0, stream>>>(gate_w, gwT);
  routing_kernel<<<T_, 256, 0, stream>>>(x, gwT, tw, ti);
  assign_kernel<<<E_, 64, 0, stream>>>(ti, counts, tlist, slot_of);

  // gate (+ shared gate fused as yb >= 64): [tok] x [K=2048] -> [1536]
  gemm_fp4_kernel<<<dim3(12, 72, 1), 256, 0, stream>>>(
      xb, xb, H_, tlist, counts, E_,
      gate_packed, (long)I_ * (H_ / 8), gate_scales, (long)(H_ / GS_) * I_,
      sh_gate_packed, sh_gate_scales,
      gbuf, 0, gsbuf, 0, H_, I_);
  // up (+ shared up)
  gemm_fp4_kernel<<<dim3(12, 72, 1), 256, 0, stream>>>(
      xb, xb, H_, tlist, counts, E_,
      up_packed, (long)I_ * (H_ / 8), up_scales, (long)(H_ / GS_) * I_,
      sh_up_packed, sh_up_scales,
      ubuf, 0, usbuf, 0, H_, I_);

  silu_mul_kernel<<<(E_ * CAP * I_ / 8 + 255) / 256, 256, 0, stream>>>(
      gbuf, ubuf, gbuf, E_ * CAP * I_ / 8);
  silu_mul_kernel<<<(T_ * I_ / 8 + 255) / 256, 256, 0, stream>>>(
      gsbuf, usbuf, gsbuf, T_ * I_ / 8);

  // down (+ shared down -> y as f32): [tok] x [K=1536] -> [2048]
  gemm_fp4_kernel<<<dim3(16, 72, 1), 256, 0, stream>>>(
      gbuf, gsbuf, I_, nullptr, counts, E_,
      down_packed, (long)H_ * (I_ / 8), down_scales, (long)(I_ / GS_) * H_,
      sh_down_packed, sh_down_scales,
      eout, 0, y, 1, I_, H_);

  combine_kernel<<<T_, 256, 0, stream>>>(y, eout, slot_of, tw);
}